// Round 6
// baseline (83.184 us; speedup 1.0000x reference)
//
#include <hip/hip_runtime.h>

#define NROWS 16384
#define DDIM  256
#define GBLK  2048   // 8 blocks/CU x 256 CUs: all co-resident (LDS 5KB, VGPR<=64)
#define RBLK  64     // phase-B blocks: each reduces 32 p1-rows and applies W

// g = (X W)(X^T (X b)) via u = Xb, v = X^T u, w2 = W v, g = X w2.
// R13: fused, fence-free barriers (R4-proven). Change vs R5: phase B was the
// bottleneck (~9us: 8 CUs doing 256 scalar coherent loads/thread, latency-
// bound). Now 64 blocks x float4 wave-coalesced loads (one latency exposure),
// and the 2nd reduce level is fused into W algebraically:
//   w2[i] = sum_j W[i].vpart_j  -> per-block W GEMV on its own 32-row
// v-partial (W cached, L2-hot) + 1 atomicAdd/thread. Phase-C X rows are
// prefetched into registers before barrier 2 (latency hides under spin).

// bars layout (uint index; one counter per 128B line = stride 32)
#define SUB1  0      // 64 lines (32 arrivals each)
#define MAIN1 2048
#define GO1   2080   // 64 lines
#define MAIN2 4128
#define GO2   4160   // 64 lines
#define REFC  6208   // untouched cell: uniform poison reference

__device__ __forceinline__ unsigned aload(const unsigned* p) {
    return __hip_atomic_load(p, __ATOMIC_RELAXED, __HIP_MEMORY_SCOPE_AGENT);
}
__device__ __forceinline__ float afload(const float* p) {
    return __hip_atomic_load(p, __ATOMIC_RELAXED, __HIP_MEMORY_SCOPE_AGENT);
}
__device__ __forceinline__ float4 afload4(const float4* p) {
    const float* f = (const float*)p;
    float4 r;
    r.x = afload(f + 0); r.y = afload(f + 1);
    r.z = afload(f + 2); r.w = afload(f + 3);
    return r;
}
__device__ __forceinline__ void astore(float* p, float v) {
    __hip_atomic_store(p, v, __ATOMIC_RELAXED, __HIP_MEMORY_SCOPE_AGENT);
}
__device__ __forceinline__ unsigned armw(unsigned* p) {
    return __hip_atomic_fetch_add(p, 1u, __ATOMIC_RELAXED, __HIP_MEMORY_SCOPE_AGENT);
}

__global__ __launch_bounds__(256, 8)
void fused(const float* __restrict__ X, const float* __restrict__ W,
           const float* __restrict__ b, float* __restrict__ p1,
           float* __restrict__ w2, unsigned* __restrict__ bars,
           float* __restrict__ g) {
    const int tid  = threadIdx.x;
    const int lane = tid & 63;
    const int wave = tid >> 6;
    const int bid  = blockIdx.x;

    __shared__ __align__(16) float sp[4 * DDIM];  // 4 KB scratch
    __shared__ __align__(16) float sv[DDIM];      // 1 KB

    const float4* X4 = (const float4*)X;

    unsigned initv = 0;
    if (tid == 0) initv = aload(&bars[REFC]);     // uniform ws poison pattern

    // ---- Phase A: t = x.b per row (butterfly), vacc += t*x; LDS-combine;
    //      unique partial row via atomic store (write-through, no RMW).
    {
        const float4 bf = ((const float4*)b)[lane];
        float4 vacc = make_float4(0.f, 0.f, 0.f, 0.f);
        const int row0 = bid * 8 + wave * 2;
        #pragma unroll
        for (int i = 0; i < 2; ++i) {
            const float4 xv = X4[(row0 + i) * 64 + lane];
            float t = xv.x * bf.x + xv.y * bf.y + xv.z * bf.z + xv.w * bf.w;
            #pragma unroll
            for (int off = 32; off; off >>= 1) t += __shfl_xor(t, off, 64);
            vacc.x += t * xv.x; vacc.y += t * xv.y;
            vacc.z += t * xv.z; vacc.w += t * xv.w;
        }
        ((float4*)&sp[wave * DDIM])[lane] = vacc;
        __syncthreads();
        const float s = sp[tid] + sp[DDIM + tid] + sp[2*DDIM + tid] + sp[3*DDIM + tid];
        astore(&p1[bid * DDIM + tid], s);
        if (bid == GBLK - 1) astore(&w2[tid], 0.f);   // clean base for phase-B RMWs
    }

    // ---- barrier 1: all 2048 arrive (hierarchical, fence-free)
    asm volatile("s_waitcnt vmcnt(0)" ::: "memory");
    __syncthreads();
    if (tid == 0) {
        const int grp = bid >> 5, mem = bid & 31;
        unsigned old = armw(&bars[SUB1 + grp * 32]);
        if (old - initv == 31u) armw(&bars[MAIN1]);
        unsigned spins = 0;
        if (mem == 0) {
            while (aload(&bars[MAIN1]) - initv < 64u) {
                __builtin_amdgcn_s_sleep(2);
                if (++spins > 800000u) break;          // hang-proof
            }
            __hip_atomic_store(&bars[GO1 + grp * 32], initv + 1u,
                               __ATOMIC_RELAXED, __HIP_MEMORY_SCOPE_AGENT);
        } else {
            while (aload(&bars[GO1 + grp * 32]) - initv == 0u) {
                __builtin_amdgcn_s_sleep(2);
                if (++spins > 800000u) break;
            }
        }
    }
    __syncthreads();

    // ---- Phase B (blocks 0..63): sum p1 rows [32*bid, 32*bid+32) float4-
    //      wide (8 independent loads/thread -> one latency exposure), LDS-
    //      combine -> 32-row v-partial; then y = W . vpart (W cached/L2) and
    //      ONE atomicAdd per thread into w2.
    if (bid < RBLK) {
        const float4* P4 = (const float4*)p1;
        float4 acc = make_float4(0.f, 0.f, 0.f, 0.f);
        const int rbase = bid * 32 + wave * 8;
        #pragma unroll
        for (int i = 0; i < 8; ++i) {
            const float4 p = afload4(&P4[(rbase + i) * 64 + lane]);
            acc.x += p.x; acc.y += p.y; acc.z += p.z; acc.w += p.w;
        }
        ((float4*)&sp[wave * DDIM])[lane] = acc;
        __syncthreads();
        sv[tid] = sp[tid] + sp[DDIM + tid] + sp[2*DDIM + tid] + sp[3*DDIM + tid];
        __syncthreads();
        const float4* W4  = (const float4*)W;   // row i at W4[i*64 ..]
        const float4* sv4 = (const float4*)sv;
        float y = 0.f;
        #pragma unroll 8
        for (int k = 0; k < 64; ++k) {
            const float4 wv = W4[tid * 64 + k];
            const float4 vv = sv4[k];
            y += wv.x * vv.x + wv.y * vv.y + wv.z * vv.z + wv.w * vv.w;
        }
        atomicAdd(&w2[tid], y);   // 16K RMWs total, fire-and-forget
    }

    // ---- prefetch phase-C X rows into registers (hides under bar-2 spin)
    const int row0 = bid * 8 + wave * 2;
    const float4 xc0 = X4[(row0 + 0) * 64 + lane];
    const float4 xc1 = X4[(row0 + 1) * 64 + lane];

    // ---- barrier 2: 64 producers signal, everyone waits (fence-free)
    asm volatile("s_waitcnt vmcnt(0)" ::: "memory");
    __syncthreads();
    if (tid == 0) {
        if (bid < RBLK) armw(&bars[MAIN2]);
        const int grp = bid >> 5, mem = bid & 31;
        unsigned spins = 0;
        if (mem == 0) {
            while (aload(&bars[MAIN2]) - initv < (unsigned)RBLK) {
                __builtin_amdgcn_s_sleep(2);
                if (++spins > 800000u) break;
            }
            __hip_atomic_store(&bars[GO2 + grp * 32], initv + 1u,
                               __ATOMIC_RELAXED, __HIP_MEMORY_SCOPE_AGENT);
        } else {
            while (aload(&bars[GO2 + grp * 32]) - initv == 0u) {
                __builtin_amdgcn_s_sleep(2);
                if (++spins > 800000u) break;
            }
        }
    }
    __syncthreads();

    // ---- Phase C: g = X w2, X rows already in registers.
    {
        sv[tid] = afload(&w2[tid]);
        __syncthreads();
        const float4 wf = ((const float4*)sv)[lane];
        float t0 = xc0.x * wf.x + xc0.y * wf.y + xc0.z * wf.z + xc0.w * wf.w;
        float t1 = xc1.x * wf.x + xc1.y * wf.y + xc1.z * wf.z + xc1.w * wf.w;
        #pragma unroll
        for (int off = 32; off; off >>= 1) {
            t0 += __shfl_xor(t0, off, 64);
            t1 += __shfl_xor(t1, off, 64);
        }
        if (lane == 0) { g[row0] = t0; g[row0 + 1] = t1; }
    }
}

extern "C" void kernel_launch(void* const* d_in, const int* in_sizes, int n_in,
                              void* d_out, int out_size, void* d_ws, size_t ws_size,
                              hipStream_t stream) {
    const float* X = (const float*)d_in[0];   // (16384, 256)
    const float* W = (const float*)d_in[1];   // (256, 256)
    const float* b = (const float*)d_in[2];   // (256,)
    float* g = (float*)d_out;                 // (16384,)

    float*    p1   = (float*)d_ws;                     // 2048*256 floats (2 MB)
    float*    w2   = p1 + GBLK * DDIM;                 // 256 floats
    unsigned* bars = (unsigned*)d_ws + 532480;         // clear of p1/w2

    fused<<<GBLK, 256, 0, stream>>>(X, W, b, p1, w2, bars, g);
}